// Round 5
// baseline (509.409 us; speedup 1.0000x reference)
//
#include <hip/hip_runtime.h>
#include <hip/hip_bf16.h>
#include <cstdint>
#include <cstddef>

typedef __bf16 bf16_t;
typedef __attribute__((ext_vector_type(8))) __bf16 bf16x8;
typedef __attribute__((ext_vector_type(4))) __bf16 bf16x4;
typedef __attribute__((ext_vector_type(4))) float f32x4;

#define DEVI static __device__ __forceinline__

DEVI void gload_lds16(const void* g, void* l) {
    __builtin_amdgcn_global_load_lds((const __attribute__((address_space(1))) void*)g,
                                     (__attribute__((address_space(3))) void*)l, 16, 0, 0);
}

#define BARR() __builtin_amdgcn_s_barrier()
#define LGKM0() do { asm volatile("s_waitcnt lgkmcnt(0)" ::: "memory"); \
                     __builtin_amdgcn_sched_barrier(0); } while (0)
#define SCHED0() __builtin_amdgcn_sched_barrier(0)
#define VMW(n) asm volatile("s_waitcnt vmcnt(" #n ")" ::: "memory")
#define SP(x) __builtin_amdgcn_s_setprio(x)

// ---------------------------------------------------------------------------
__global__ __launch_bounds__(256)
void transpose_cast_kernel(const float* __restrict__ W, bf16_t* __restrict__ Wt,
                           int K, int N) {
    int idx = blockIdx.x * 256 + threadIdx.x;
    if (idx >= N * K) return;
    int n = idx / K;
    int k = idx - n * K;
    Wt[idx] = (bf16_t)W[(size_t)k * N + n];
}

// cast x[:, :256] f32 -> bf16 (A operand of layer 1)
__global__ __launch_bounds__(256)
void cast_x_kernel(const float* __restrict__ x, bf16_t* __restrict__ xb) {
    int g = blockIdx.x * 256 + threadIdx.x;     // over B*32
    int row = g >> 5, c8 = (g & 31) * 8;
    const float4 v0 = *(const float4*)(x + (size_t)row * 512 + c8);
    const float4 v1 = *(const float4*)(x + (size_t)row * 512 + c8 + 4);
    bf16x8 o;
    o[0] = (bf16_t)v0.x; o[1] = (bf16_t)v0.y; o[2] = (bf16_t)v0.z; o[3] = (bf16_t)v0.w;
    o[4] = (bf16_t)v1.x; o[5] = (bf16_t)v1.y; o[6] = (bf16_t)v1.z; o[7] = (bf16_t)v1.w;
    *(bf16x8*)(xb + (size_t)row * 256 + c8) = o;
}

// W4 column-permuted transpose: W4p[vt][k]; within N-tile bn, virtual col
// v = v16*16 + c: v16 even -> shift col (bn*128 + (v16>>1)*16 + c),
//                 v16 odd  -> scale col (256 + same). Bias likewise.
__global__ __launch_bounds__(256)
void permute_w4_kernel(const float* __restrict__ W4, bf16_t* __restrict__ W4p,
                       const float* __restrict__ b4, float* __restrict__ b4p) {
    int idx = blockIdx.x * 256 + threadIdx.x;   // over 512*1024
    int vt = idx >> 10, k = idx & 1023;
    int bn = vt >> 8, v = vt & 255;
    int v16 = v >> 4, c = v & 15;
    int tcol = bn * 128 + (v16 >> 1) * 16 + c;
    int col = (v16 & 1) ? 256 + tcol : tcol;
    W4p[idx] = (bf16_t)W4[(size_t)k * 512 + col];
    if (k == 0) b4p[vt] = b4[col];
}

// ---------------------------------------------------------------------------
// Persistent 8-phase 256x256 GEMM. Grid = 256 (1 block/CU). Each block runs
// TPB output tiles through ONE continuous pipeline: global K-tile g in
// [0, TPB*2*NI); staging for tile t+1 issues during tile t's last phases.
// bn fixed per block (B panel L2-hot); bm walks TPB consecutive tiles
// (A streamed once). Mid-tile epilogue between P8 and next P1, no drain.
// MODE 0: relu + bf16 out. MODE 2: fused coupling epilogue.
// ---------------------------------------------------------------------------
#define LOAD_A(P, KK) do { \
    const char* _s = lds + (P) * 65536 + (KK) * 16384; \
    _Pragma("unroll") \
    for (int m = 0; m < 8; ++m) af[m] = *(const bf16x8*)(_s + aOff[m]); \
} while (0)

#define LOAD_B(P, KK, NQ) do { \
    const char* _s = lds + (P) * 65536 + 32768 + (KK) * 16384; \
    bfr[0] = *(const bf16x8*)(_s + bOff[(NQ)][0]); \
    bfr[1] = *(const bf16x8*)(_s + bOff[(NQ)][1]); \
} while (0)

#define MFMA16(NQ) do { \
    _Pragma("unroll") \
    for (int m = 0; m < 8; ++m) { \
        acc[m][(NQ)*2+0] = __builtin_amdgcn_mfma_f32_16x16x32_bf16(bfr[0], af[m], acc[m][(NQ)*2+0], 0, 0, 0); \
        acc[m][(NQ)*2+1] = __builtin_amdgcn_mfma_f32_16x16x32_bf16(bfr[1], af[m], acc[m][(NQ)*2+1], 0, 0, 0); \
    } \
} while (0)

template<int MODE, int NI, int TPB>
__global__ __launch_bounds__(512, 2)
void gemm8_kernel(const bf16_t* __restrict__ A, const bf16_t* __restrict__ Bt,
                  const float* __restrict__ bias, void* __restrict__ Cp,
                  const float* __restrict__ x, float* __restrict__ part,
                  int N, int K, int gx) {
    constexpr int KT  = 2 * NI;        // K-tiles per output tile
    constexpr int TOT = NI * TPB;      // iteration-pairs total
    __shared__ __align__(16) char lds[131072];

    const int tid = threadIdx.x;
    const int bid = blockIdx.x;
    const int xcd = bid & 7, bidx = bid >> 3;
    const int bn = bidx % gx;                  // fixed per block
    const int mgrp = bidx / gx;
    const int colBase = bn * 256;
    const int l  = tid & 63;
    const int w  = tid >> 6;
    const int wm = w >> 2, wn = w & 3;
    const int lr = l & 15, lq = l >> 4;
    const int qa = lq ^ ((lr >> 1) & 3);       // swizzled chunk for reads

    auto rowBaseOf = [&](int t) { return (xcd * 32 + mgrp * TPB + t) * 256; };

    int aOff[8];
#pragma unroll
    for (int m = 0; m < 8; ++m) aOff[m] = (wm * 128 + m * 16 + lr) * 64 + qa * 16;
    int bOff[2][2];
#pragma unroll
    for (int nq = 0; nq < 2; ++nq)
#pragma unroll
        for (int nf = 0; nf < 2; ++nf)
            bOff[nq][nf] = (nq * 128 + wn * 32 + nf * 16 + lr) * 64 + qa * 16;

    // staging coords (pre-swizzled source)
    const int ca8 = ((tid & 3) ^ ((tid >> 3) & 3)) * 8;
    const int sar = tid >> 2;
    const int sbr = ((tid >> 7) & 3) * 64 + ((tid >> 2) & 31);

    auto STAGE_A = [&](int g, int kk) {        // one A k-half plane (2 issues)
        char* dst = lds + (g & 1) * 65536 + kk * 16384;
        const int rb = rowBaseOf(g / KT);
        const int kt = g & (KT - 1);
#pragma unroll
        for (int h = 0; h < 2; ++h)
            gload_lds16(A + (size_t)(rb + h * 128 + sar) * K + kt * 64 + kk * 32 + ca8,
                        dst + h * 8192 + tid * 16);
    };
    auto STAGE_B = [&](int g, int kk, int nq) { // one B (nq,kk) band (1 issue)
        char* dst = lds + (g & 1) * 65536 + 32768 + kk * 16384 + nq * 8192;
        const int kt = g & (KT - 1);
        gload_lds16(Bt + (size_t)(colBase + sbr + nq * 32) * K + kt * 64 + kk * 32 + ca8,
                    dst + tid * 16);
    };

    f32x4 acc[8][4];
    const f32x4 zero = {0.f, 0.f, 0.f, 0.f};
#pragma unroll
    for (int m = 0; m < 8; ++m)
#pragma unroll
        for (int n = 0; n < 4; ++n) acc[m][n] = zero;
    bf16x8 af[8], bfr[2];

    // ---- epilogue for tile tt (also re-zeroes acc) ----
    auto epi = [&](int tt) {
        float4 bv[4];
#pragma unroll
        for (int n = 0; n < 4; ++n)
            bv[n] = *(const float4*)(bias + colBase + wn * 64 + n * 16 + lq * 4);
        const int rowBase = rowBaseOf(tt);
        const int row0 = rowBase + wm * 128;
        if (MODE == 0) {
            bf16_t* C = (bf16_t*)Cp;
#pragma unroll
            for (int m = 0; m < 8; ++m) {
                const int row = row0 + m * 16 + lr;
#pragma unroll
                for (int n = 0; n < 4; ++n) {
                    bf16x4 pv;
#pragma unroll
                    for (int r = 0; r < 4; ++r) {
                        float v = acc[m][n][r] + ((const float*)&bv[n])[r];
                        pv[r] = (bf16_t)fmaxf(v, 0.f);
                    }
                    *(bf16x4*)(C + (size_t)row * N + colBase + wn * 64 + n * 16 + lq * 4) = pv;
                }
            }
        } else {
            const int B = 65536;
            float* out = (float*)Cp;
#pragma unroll
            for (int i2 = 0; i2 < 16; ++i2) {
                int idx2 = i2 * 512 + tid;
                int rr = idx2 >> 5, c4 = idx2 & 31;
                *(float4*)(out + (size_t)(rowBase + rr) * 512 + bn * 128 + c4 * 4) =
                    *(const float4*)(x + (size_t)(rowBase + rr) * 512 + bn * 128 + c4 * 4);
            }
#pragma unroll
            for (int m = 0; m < 8; ++m) {
                const int row = row0 + m * 16 + lr;
                float lsum = 0.f;
#pragma unroll
                for (int p = 0; p < 2; ++p) {
                    const int tcol = bn * 128 + wn * 32 + p * 16 + lq * 4;
                    const float4 xt = *(const float4*)(x + (size_t)row * 512 + 256 + tcol);
                    float4 ov;
#pragma unroll
                    for (int r = 0; r < 4; ++r) {
                        float sh = acc[m][2 * p][r]     + ((const float*)&bv[2 * p])[r];
                        float u  = acc[m][2 * p + 1][r] + ((const float*)&bv[2 * p + 1])[r];
                        float s  = 1.f / (1.f + __expf(-(u + 2.f))) + 0.001f;
                        ((float*)&ov)[r] = ((const float*)&xt)[r] * s + sh;
                        lsum += __logf(s);
                    }
                    *(float4*)(out + (size_t)row * 512 + 256 + tcol) = ov;
                }
                lsum += __shfl_xor(lsum, 16);
                lsum += __shfl_xor(lsum, 32);
                if (lq == 0) part[(size_t)(bn * 4 + wn) * B + row] = lsum;
            }
        }
#pragma unroll
        for (int m = 0; m < 8; ++m)
#pragma unroll
            for (int n = 0; n < 4; ++n) acc[m][n] = zero;
    };

    // ---- prologue: g0 fully (8), g1 partial (5); 5 left in flight ----
    STAGE_B(0, 0, 0); STAGE_A(0, 0); STAGE_B(0, 0, 1); STAGE_B(0, 1, 0);
    STAGE_A(0, 1);    STAGE_B(0, 1, 1);
    STAGE_B(1, 0, 0); STAGE_A(1, 0); STAGE_B(1, 0, 1); STAGE_B(1, 1, 0);
    VMW(5); BARR();

#pragma unroll 1
    for (int i = 0; i < TOT - 1; ++i) {
        const int tb = 2 * i + 1, tc = 2 * i + 2, td = 2 * i + 3;
        LOAD_A(0, 0); LOAD_B(0, 0, 0); STAGE_A(tb, 1); STAGE_B(tb, 1, 1);
        SCHED0(); BARR(); LGKM0();
        SP(1); MFMA16(0); SP(0); SCHED0(); BARR();
        LOAD_B(0, 0, 1); STAGE_B(tc, 0, 0);
        SCHED0(); BARR(); LGKM0();
        SP(1); MFMA16(1); SP(0); SCHED0(); BARR();
        LOAD_A(0, 1); LOAD_B(0, 1, 0); STAGE_A(tc, 0);
        SCHED0(); BARR(); LGKM0();
        SP(1); MFMA16(0); SP(0); SCHED0(); BARR();
        LOAD_B(0, 1, 1); STAGE_B(tc, 0, 1); STAGE_B(tc, 1, 0);
        SCHED0(); BARR(); LGKM0();
        SP(1); MFMA16(1); SP(0); VMW(5); SCHED0(); BARR();
        LOAD_A(1, 0); LOAD_B(1, 0, 0); STAGE_A(tc, 1); STAGE_B(tc, 1, 1);
        SCHED0(); BARR(); LGKM0();
        SP(1); MFMA16(0); SP(0); SCHED0(); BARR();
        LOAD_B(1, 0, 1); STAGE_B(td, 0, 0);
        SCHED0(); BARR(); LGKM0();
        SP(1); MFMA16(1); SP(0); SCHED0(); BARR();
        LOAD_A(1, 1); LOAD_B(1, 1, 0); STAGE_A(td, 0);
        SCHED0(); BARR(); LGKM0();
        SP(1); MFMA16(0); SP(0); SCHED0(); BARR();
        LOAD_B(1, 1, 1); STAGE_B(td, 0, 1); STAGE_B(td, 1, 0);
        SCHED0(); BARR(); LGKM0();
        SP(1); MFMA16(1); SP(0); VMW(5); SCHED0(); BARR();
        // ---- tile boundary: store + re-zero, pipeline keeps flowing ----
        if (((i + 1) & (NI - 1)) == 0) epi((i + 1) / NI - 1);
    }
    // ---- final pair: complete last K-tile's staging only; drain ----
    {
        const int tb = 2 * TOT - 1;
        LOAD_A(0, 0); LOAD_B(0, 0, 0); STAGE_A(tb, 1); STAGE_B(tb, 1, 1);
        SCHED0(); BARR(); LGKM0();
        SP(1); MFMA16(0); SP(0); SCHED0(); BARR();
        LOAD_B(0, 0, 1);
        SCHED0(); BARR(); LGKM0();
        SP(1); MFMA16(1); SP(0); SCHED0(); BARR();
        LOAD_A(0, 1); LOAD_B(0, 1, 0);
        SCHED0(); BARR(); LGKM0();
        SP(1); MFMA16(0); SP(0); SCHED0(); BARR();
        LOAD_B(0, 1, 1);
        SCHED0(); BARR(); LGKM0();
        SP(1); MFMA16(1); SP(0); VMW(0); SCHED0(); BARR();
        LOAD_A(1, 0); LOAD_B(1, 0, 0);
        SCHED0(); BARR(); LGKM0();
        SP(1); MFMA16(0); SP(0); SCHED0(); BARR();
        LOAD_B(1, 0, 1);
        SCHED0(); BARR(); LGKM0();
        SP(1); MFMA16(1); SP(0); SCHED0(); BARR();
        LOAD_A(1, 1); LOAD_B(1, 1, 0);
        SCHED0(); BARR(); LGKM0();
        SP(1); MFMA16(0); SP(0); SCHED0(); BARR();
        LOAD_B(1, 1, 1);
        SCHED0(); BARR(); LGKM0();
        SP(1); MFMA16(1); SP(0);
        epi(TPB - 1);
    }
}

__global__ __launch_bounds__(256)
void lad_reduce_kernel(const float* __restrict__ part, float* __restrict__ lad) {
    const int B = 65536;
    int rIdx = blockIdx.x * 256 + threadIdx.x;
    float s = 0.f;
#pragma unroll
    for (int j = 0; j < 8; ++j) s += part[(size_t)j * B + rIdx];
    lad[rIdx] = s;
}

// ---------------------------------------------------------------------------
extern "C" void kernel_launch(void* const* d_in, const int* in_sizes, int n_in,
                              void* d_out, int out_size, void* d_ws, size_t ws_size,
                              hipStream_t stream) {
    const int B = 65536, D_ID = 256, H = 1024, NP = 512;

    const float* x  = (const float*)d_in[0];
    const float* W1 = (const float*)d_in[1];
    const float* b1 = (const float*)d_in[2];
    const float* W2 = (const float*)d_in[3];
    const float* b2 = (const float*)d_in[4];
    const float* W3 = (const float*)d_in[5];
    const float* b3 = (const float*)d_in[6];
    const float* W4 = (const float*)d_in[7];
    const float* b4 = (const float*)d_in[8];

    float* out = (float*)d_out;
    float* lad = out + (size_t)B * 512;

    char* ws = (char*)d_ws;
    const size_t hbytes = (size_t)B * H * sizeof(bf16_t);      // 128 MiB
    bf16_t* hA   = (bf16_t*)ws;
    bf16_t* hB   = (bf16_t*)(ws + hbytes);
    bf16_t* xb   = (bf16_t*)(ws + hbytes);                     // alias hB (dead before L2)
    float*  part = (float*) (ws + hbytes);                     // alias hB (dead after L3)
    bf16_t* W1t  = (bf16_t*)(ws + 2 * hbytes);
    bf16_t* W2t  = W1t + (size_t)H * D_ID;
    bf16_t* W3t  = W2t + (size_t)H * H;
    bf16_t* W4p  = W3t + (size_t)H * H;
    float*  b4p  = (float*)(W4p + (size_t)NP * H);

    dim3 blk(256), blk8(512);
    cast_x_kernel<<<dim3(B * 32 / 256), blk, 0, stream>>>(x, xb);
    transpose_cast_kernel<<<dim3((H * D_ID + 255) / 256), blk, 0, stream>>>(W1, W1t, D_ID, H);
    transpose_cast_kernel<<<dim3((H * H + 255) / 256),    blk, 0, stream>>>(W2, W2t, H, H);
    transpose_cast_kernel<<<dim3((H * H + 255) / 256),    blk, 0, stream>>>(W3, W3t, H, H);
    permute_w4_kernel<<<dim3(NP * H / 256), blk, 0, stream>>>(W4, W4p, b4, b4p);

    // all GEMMs: persistent, grid 256 = 1 block/CU
    // layer 1: K=256 (NI=2), 4 tiles/block
    gemm8_kernel<0, 2, 4><<<dim3(256), blk8, 0, stream>>>(xb, W1t, b1, hA, nullptr, nullptr, H, D_ID, 4);
    // layers 2,3: K=1024 (NI=8), 4 tiles/block
    gemm8_kernel<0, 8, 4><<<dim3(256), blk8, 0, stream>>>(hA, W2t, b2, hB, nullptr, nullptr, H, H, 4);
    gemm8_kernel<0, 8, 4><<<dim3(256), blk8, 0, stream>>>(hB, W3t, b3, hA, nullptr, nullptr, H, H, 4);
    // layer 4: N=512 (NI=8), 2 tiles/block, fused coupling epilogue
    gemm8_kernel<2, 8, 2><<<dim3(256), blk8, 0, stream>>>(hA, W4p, b4p, out, x, part, NP, H, 2);

    lad_reduce_kernel<<<dim3(B / 256), blk, 0, stream>>>(part, lad);
}

// Round 6
// 501.815 us; speedup vs baseline: 1.0151x; 1.0151x over previous
//
#include <hip/hip_runtime.h>
#include <hip/hip_bf16.h>
#include <cstdint>
#include <cstddef>

typedef __bf16 bf16_t;
typedef __attribute__((ext_vector_type(8))) __bf16 bf16x8;
typedef __attribute__((ext_vector_type(4))) __bf16 bf16x4;
typedef __attribute__((ext_vector_type(4))) float f32x4;

#define DEVI static __device__ __forceinline__

DEVI void gload_lds16(const void* g, void* l) {
    __builtin_amdgcn_global_load_lds((const __attribute__((address_space(1))) void*)g,
                                     (__attribute__((address_space(3))) void*)l, 16, 0, 0);
}

#define BARR() __builtin_amdgcn_s_barrier()
#define LGKM0() do { asm volatile("s_waitcnt lgkmcnt(0)" ::: "memory"); \
                     __builtin_amdgcn_sched_barrier(0); } while (0)
#define SCHED0() __builtin_amdgcn_sched_barrier(0)
#define VMW(n) asm volatile("s_waitcnt vmcnt(" #n ")" ::: "memory")
#define SP(x) __builtin_amdgcn_s_setprio(x)

// ---------------------------------------------------------------------------
__global__ __launch_bounds__(256)
void transpose_cast_kernel(const float* __restrict__ W, bf16_t* __restrict__ Wt,
                           int K, int N) {
    int idx = blockIdx.x * 256 + threadIdx.x;
    if (idx >= N * K) return;
    int n = idx / K;
    int k = idx - n * K;
    Wt[idx] = (bf16_t)W[(size_t)k * N + n];
}

// cast x[:, :256] f32 -> bf16 (A operand of layer 1)
__global__ __launch_bounds__(256)
void cast_x_kernel(const float* __restrict__ x, bf16_t* __restrict__ xb) {
    int g = blockIdx.x * 256 + threadIdx.x;     // over B*32
    int row = g >> 5, c8 = (g & 31) * 8;
    const float4 v0 = *(const float4*)(x + (size_t)row * 512 + c8);
    const float4 v1 = *(const float4*)(x + (size_t)row * 512 + c8 + 4);
    bf16x8 o;
    o[0] = (bf16_t)v0.x; o[1] = (bf16_t)v0.y; o[2] = (bf16_t)v0.z; o[3] = (bf16_t)v0.w;
    o[4] = (bf16_t)v1.x; o[5] = (bf16_t)v1.y; o[6] = (bf16_t)v1.z; o[7] = (bf16_t)v1.w;
    *(bf16x8*)(xb + (size_t)row * 256 + c8) = o;
}

// W4 column-permuted transpose (virtual col v16 even -> shift, odd -> scale)
__global__ __launch_bounds__(256)
void permute_w4_kernel(const float* __restrict__ W4, bf16_t* __restrict__ W4p,
                       const float* __restrict__ b4, float* __restrict__ b4p) {
    int idx = blockIdx.x * 256 + threadIdx.x;   // over 512*1024
    int vt = idx >> 10, k = idx & 1023;
    int bn = vt >> 8, v = vt & 255;
    int v16 = v >> 4, c = v & 15;
    int tcol = bn * 128 + (v16 >> 1) * 16 + c;
    int col = (v16 & 1) ? 256 + tcol : tcol;
    W4p[idx] = (bf16_t)W4[(size_t)k * 512 + col];
    if (k == 0) b4p[vt] = b4[col];
}

// ---------------------------------------------------------------------------
// Persistent 256x256 GEMM, BK=32, 4 LDS buffers (4 x 32KB), 2 phases/K-tile,
// register-pipelined operands (reads for phase p+1 issued in phase p),
// 1 barrier/phase, counted vmcnt(6) with 3-K-tile staging depth.
// 8 waves 2Mx4N, per-wave 128x64, swapped-operand MFMA (C^T frags).
// MODE 0: relu + bf16 out. MODE 2: fused coupling epilogue.
// ---------------------------------------------------------------------------
#define RD_A(DST, g) do { \
    const char* _b = lds + ((g) & 3) * 32768; \
    _Pragma("unroll") \
    for (int m = 0; m < 8; ++m) DST[m] = *(const bf16x8*)(_b + aOff + m * 1024); \
} while (0)

#define RD_B(DST, g, J0) do { \
    const char* _b = lds + ((g) & 3) * 32768 + 16384; \
    DST[0] = *(const bf16x8*)(_b + bOff + (J0) * 1024); \
    DST[1] = *(const bf16x8*)(_b + bOff + (J0 + 1) * 1024); \
} while (0)

#define MM2(BSET, ASET, J0) do { \
    _Pragma("unroll") \
    for (int m = 0; m < 8; ++m) { \
        acc[m][J0]     = __builtin_amdgcn_mfma_f32_16x16x32_bf16(BSET[0], ASET[m], acc[m][J0], 0, 0, 0); \
        acc[m][J0 + 1] = __builtin_amdgcn_mfma_f32_16x16x32_bf16(BSET[1], ASET[m], acc[m][J0 + 1], 0, 0, 0); \
    } \
} while (0)

// phase0(t): MFMA on (afS, b0) -> cols 0,1; pre-read b1 <- B(t, 2..3); stage A(t+3)
#define PHASE0(ASET, t) do { \
    RD_B(b1, (t), 2); \
    STAGE_A((t) + 3); \
    SCHED0(); \
    SP(1); MM2(b0, ASET, 0); SP(0); \
    LGKM0(); BARR(); \
} while (0)

// phase1(t): vmcnt; pre-read afN <- A(t+1), b0 <- B(t+1, 0..1); stage B(t+3);
//            MFMA on (afS, b1) -> cols 2,3
#define PHASE1(ASET, ANXT, t, W0) do { \
    if (W0) { VMW(0); } else { VMW(6); } \
    RD_A(ANXT, (t) + 1); \
    RD_B(b0, (t) + 1, 0); \
    STAGE_B((t) + 3); \
    SCHED0(); \
    SP(1); MM2(b1, ASET, 2); SP(0); \
    LGKM0(); BARR(); \
} while (0)

template<int MODE, int NI, int TPB>
__global__ __launch_bounds__(512, 2)
void gemmP_kernel(const bf16_t* __restrict__ A, const bf16_t* __restrict__ Bt,
                  const float* __restrict__ bias, void* __restrict__ Cp,
                  const float* __restrict__ x, float* __restrict__ part,
                  int N, int K, int gx) {
    constexpr int GT = NI * TPB;               // K-tiles in the block's stream
    __shared__ __align__(16) char lds[131072]; // 4 buffers x (A 16KB + B 16KB)

    const int tid = threadIdx.x;
    const int bid = blockIdx.x;
    const int xcd = bid & 7, bidx = bid >> 3;
    const int bn = bidx % gx;                  // fixed per block
    const int mgrp = bidx / gx;
    const int colBase = bn * 256;
    const int l  = tid & 63;
    const int w  = tid >> 6;
    const int wm = w >> 2, wn = w & 3;
    const int lr = l & 15, lq = l >> 4;
    const int qa = lq ^ ((lr >> 1) & 3);       // swizzled 16B chunk for reads

    const int aOff = (wm * 128 + lr) * 64 + qa * 16;            // + m*1024
    const int bOff = (wn * 64 + lr) * 64 + qa * 16;             // + j*1024

    // staging coords (pre-swizzled source)
    const int sar = tid >> 2;                                   // row 0..127
    const int ca8 = ((tid & 3) ^ ((sar >> 1) & 3)) * 8;         // swizzled src chunk

    auto rowBaseOf = [&](int tt) { return (xcd * 32 + mgrp * TPB + tt) * 256; };

    auto STAGE_A = [&](int gd) {               // A 16KB of K-tile gd (2 issues)
        const int gs = gd < GT ? gd : GT - 1;  // clamp: dummy re-stage at tail
        char* dst = lds + (gd & 3) * 32768 + tid * 16;
        const bf16_t* src = A + (size_t)(rowBaseOf(gs / NI) + sar) * K
                              + (gs % NI) * 32 + ca8;
#pragma unroll
        for (int u = 0; u < 2; ++u)
            gload_lds16(src + (size_t)u * 128 * K, dst + u * 8192);
    };
    auto STAGE_B = [&](int gd) {               // B 16KB of K-tile gd (2 issues)
        const int gs = gd < GT ? gd : GT - 1;
        char* dst = lds + (gd & 3) * 32768 + 16384 + tid * 16;
        const bf16_t* src = Bt + (size_t)(colBase + sar) * K
                               + (gs % NI) * 32 + ca8;
#pragma unroll
        for (int u = 0; u < 2; ++u)
            gload_lds16(src + (size_t)u * 128 * K, dst + u * 8192);
    };

    f32x4 acc[8][4];
    const f32x4 zero = {0.f, 0.f, 0.f, 0.f};
#pragma unroll
    for (int m = 0; m < 8; ++m)
#pragma unroll
        for (int n = 0; n < 4; ++n) acc[m][n] = zero;
    bf16x8 afX[8], afY[8], b0[2], b1[2];

    // ---- epilogue for output tile tt (stores + re-zero acc) ----
    auto epi = [&](int tt) {
        float4 bv[4];
#pragma unroll
        for (int n = 0; n < 4; ++n)
            bv[n] = *(const float4*)(bias + colBase + wn * 64 + n * 16 + lq * 4);
        const int rowBase = rowBaseOf(tt);
        const int row0 = rowBase + wm * 128;
        if (MODE == 0) {
            bf16_t* C = (bf16_t*)Cp;
#pragma unroll
            for (int m = 0; m < 8; ++m) {
                const int row = row0 + m * 16 + lr;
#pragma unroll
                for (int n = 0; n < 4; ++n) {
                    bf16x4 pv;
#pragma unroll
                    for (int r = 0; r < 4; ++r) {
                        float v = acc[m][n][r] + ((const float*)&bv[n])[r];
                        pv[r] = (bf16_t)fmaxf(v, 0.f);
                    }
                    *(bf16x4*)(C + (size_t)row * N + colBase + wn * 64 + n * 16 + lq * 4) = pv;
                }
            }
        } else {
            const int B = 65536;
            float* out = (float*)Cp;
#pragma unroll
            for (int i2 = 0; i2 < 16; ++i2) {
                int idx2 = i2 * 512 + tid;
                int rr = idx2 >> 5, c4 = idx2 & 31;
                *(float4*)(out + (size_t)(rowBase + rr) * 512 + bn * 128 + c4 * 4) =
                    *(const float4*)(x + (size_t)(rowBase + rr) * 512 + bn * 128 + c4 * 4);
            }
#pragma unroll
            for (int m = 0; m < 8; ++m) {
                const int row = row0 + m * 16 + lr;
                float lsum = 0.f;
#pragma unroll
                for (int p = 0; p < 2; ++p) {
                    const int tcol = bn * 128 + wn * 32 + p * 16 + lq * 4;
                    const float4 xt = *(const float4*)(x + (size_t)row * 512 + 256 + tcol);
                    float4 ov;
#pragma unroll
                    for (int r = 0; r < 4; ++r) {
                        float sh = acc[m][2 * p][r]     + ((const float*)&bv[2 * p])[r];
                        float u  = acc[m][2 * p + 1][r] + ((const float*)&bv[2 * p + 1])[r];
                        float s  = 1.f / (1.f + __expf(-(u + 2.f))) + 0.001f;
                        ((float*)&ov)[r] = ((const float*)&xt)[r] * s + sh;
                        lsum += __logf(s);
                    }
                    *(float4*)(out + (size_t)row * 512 + 256 + tcol) = ov;
                }
                lsum += __shfl_xor(lsum, 16);
                lsum += __shfl_xor(lsum, 32);
                if (lq == 0) part[(size_t)(bn * 4 + wn) * B + row] = lsum;
            }
        }
#pragma unroll
        for (int m = 0; m < 8; ++m)
#pragma unroll
            for (int n = 0; n < 4; ++n) acc[m][n] = zero;
    };

    // ---- prologue: stage tiles 0,1,2 (12 issues); pre-read tile 0 ops ----
    STAGE_A(0); STAGE_B(0); STAGE_A(1); STAGE_B(1); STAGE_A(2); STAGE_B(2);
    VMW(8);     // tile 0 complete; tiles 1,2 (8 issues) in flight
    BARR();
    RD_A(afX, 0); RD_B(b0, 0, 0);
    LGKM0();

#pragma unroll 1
    for (int g = 0; g < GT / 2; ++g) {
        const int ta = 2 * g, tb = 2 * g + 1;
        const bool w0 = (ta > 0) && ((ta & (NI - 1)) == 0);  // drain after epilogue
        PHASE0(afX, ta);
        PHASE1(afX, afY, ta, w0);
        PHASE0(afY, tb);
        PHASE1(afY, afX, tb, false);
        if (((tb + 1) & (NI - 1)) == 0) epi((tb + 1) / NI - 1);
    }
}

__global__ __launch_bounds__(256)
void lad_reduce_kernel(const float* __restrict__ part, float* __restrict__ lad) {
    const int B = 65536;
    int rIdx = blockIdx.x * 256 + threadIdx.x;
    float s = 0.f;
#pragma unroll
    for (int j = 0; j < 8; ++j) s += part[(size_t)j * B + rIdx];
    lad[rIdx] = s;
}

// ---------------------------------------------------------------------------
extern "C" void kernel_launch(void* const* d_in, const int* in_sizes, int n_in,
                              void* d_out, int out_size, void* d_ws, size_t ws_size,
                              hipStream_t stream) {
    const int B = 65536, D_ID = 256, H = 1024, NP = 512;

    const float* x  = (const float*)d_in[0];
    const float* W1 = (const float*)d_in[1];
    const float* b1 = (const float*)d_in[2];
    const float* W2 = (const float*)d_in[3];
    const float* b2 = (const float*)d_in[4];
    const float* W3 = (const float*)d_in[5];
    const float* b3 = (const float*)d_in[6];
    const float* W4 = (const float*)d_in[7];
    const float* b4 = (const float*)d_in[8];

    float* out = (float*)d_out;
    float* lad = out + (size_t)B * 512;

    char* ws = (char*)d_ws;
    const size_t hbytes = (size_t)B * H * sizeof(bf16_t);      // 128 MiB
    bf16_t* hA   = (bf16_t*)ws;
    bf16_t* hB   = (bf16_t*)(ws + hbytes);
    bf16_t* xb   = (bf16_t*)(ws + hbytes);                     // alias hB (dead before L2)
    float*  part = (float*) (ws + hbytes);                     // alias hB (dead after L3)
    bf16_t* W1t  = (bf16_t*)(ws + 2 * hbytes);
    bf16_t* W2t  = W1t + (size_t)H * D_ID;
    bf16_t* W3t  = W2t + (size_t)H * H;
    bf16_t* W4p  = W3t + (size_t)H * H;
    float*  b4p  = (float*)(W4p + (size_t)NP * H);

    dim3 blk(256), blk8(512);
    cast_x_kernel<<<dim3(B * 32 / 256), blk, 0, stream>>>(x, xb);
    transpose_cast_kernel<<<dim3((H * D_ID + 255) / 256), blk, 0, stream>>>(W1, W1t, D_ID, H);
    transpose_cast_kernel<<<dim3((H * H + 255) / 256),    blk, 0, stream>>>(W2, W2t, H, H);
    transpose_cast_kernel<<<dim3((H * H + 255) / 256),    blk, 0, stream>>>(W3, W3t, H, H);
    permute_w4_kernel<<<dim3(NP * H / 256), blk, 0, stream>>>(W4, W4p, b4, b4p);

    // all GEMMs persistent: grid 256 = 1 block/CU
    // layer 1: K=256 (NI=8 K-tiles of 32), 4 tiles/block
    gemmP_kernel<0, 8, 4><<<dim3(256), blk8, 0, stream>>>(xb, W1t, b1, hA, nullptr, nullptr, H, D_ID, 4);
    // layers 2,3: K=1024 (NI=32), 4 tiles/block
    gemmP_kernel<0, 32, 4><<<dim3(256), blk8, 0, stream>>>(hA, W2t, b2, hB, nullptr, nullptr, H, H, 4);
    gemmP_kernel<0, 32, 4><<<dim3(256), blk8, 0, stream>>>(hB, W3t, b3, hA, nullptr, nullptr, H, H, 4);
    // layer 4: N=512 (NI=32), 2 tiles/block, fused coupling epilogue
    gemmP_kernel<2, 32, 2><<<dim3(256), blk8, 0, stream>>>(hA, W4p, b4p, out, x, part, NP, H, 2);

    lad_reduce_kernel<<<dim3(B / 256), blk, 0, stream>>>(part, lad);
}